// Round 4
// baseline (16012.009 us; speedup 1.0000x reference)
//
#include <hip/hip_runtime.h>

#define B_    64
#define S_    1024
#define H_    512
#define KTOT  1024              // I + H
#define BH    (B_ * H_)         // 32768 elements per h-state buffer
#define NWG   64                // 32 WGs per layer

typedef short  v8s __attribute__((ext_vector_type(8)));
typedef float  v4f __attribute__((ext_vector_type(4)));

__device__ __forceinline__ unsigned short f2b_rne(float f) {   // exact round-nearest-even
    union { float f; unsigned int i; } c; c.f = f;
    unsigned int x = c.i;
    return (unsigned short)((x + 0x7fffu + ((x >> 16) & 1u)) >> 16);
}

// pack two fp32 -> bf16x2 dword (round-half-up via +0x8000, then byte-perm)
__device__ __forceinline__ unsigned rnpack(float a, float b) {
    union { float f; unsigned u; } x, y; x.f = a; y.f = b;
    return __builtin_amdgcn_perm(y.u + 0x8000u, x.u + 0x8000u, 0x07060302u);
}

union frag_u { v8s s; unsigned u[4]; };

__device__ __forceinline__ v8s pack8(const float4 f0, const float4 f1) {
    frag_u r;
    r.u[0] = rnpack(f0.x, f0.y);
    r.u[1] = rnpack(f0.z, f0.w);
    r.u[2] = rnpack(f1.x, f1.y);
    r.u[3] = rnpack(f1.z, f1.w);
    return r.s;
}

// LDS layout for transposed weight slice: column n in [0,16), k in [0,1024).
// XOR-octet swizzle: no pad bytes, 16B-aligned frag reads, 2-way max conflict (free).
__device__ __forceinline__ int bidx(int n, int k) {
    int k8 = k >> 3;
    return (n << 10) + (((k8 ^ (n & 7)) << 3) | (k & 7));
}

__global__ __launch_bounds__(256) void gru_fused(
    const float* __restrict__ Xin,   // (B, S, 512) fp32
    const float* __restrict__ Wg,    // (2, 1024, 512)
    const float* __restrict__ bgp,   // (2, 512)
    const float* __restrict__ Wi,    // (2, 512, 512)
    const float* __restrict__ bip,   // (2, 512)
    const float* __restrict__ Wh,    // (2, 512, 512)
    float* __restrict__ Yout,        // (B, S, 512) final-layer output
    float* __restrict__ hfin,        // (2, B, 512) final hidden
    float* __restrict__ h0buf,       // 2 x (B,512) fp32 layer-0 h double-buffer (zeroed)
    float* __restrict__ h1buf,       // 2 x (B,512) fp32 layer-1 h double-buffer (zeroed)
    unsigned int* __restrict__ ctr)  // monotonic barrier counter (zeroed)
{
    __shared__ unsigned short Bz[16 * KTOT];  // 32 KB  [Wgx; Wgh] cols n0..n0+15, transposed, bf16
    __shared__ unsigned short Bc[16 * KTOT];  // 32 KB  [Wi ; Wh ] cols, transposed, bf16

    const int tid   = threadIdx.x;
    const int layer = blockIdx.x >> 5;        // 0 or 1
    const int n0    = (blockIdx.x & 31) * 16; // column group

    const float* Wgs = Wg + (size_t)layer * KTOT * 512;
    const float* Wis = Wi + (size_t)layer * 512 * 512;
    const float* Whs = Wh + (size_t)layer * 512 * 512;

    // one-time: transpose + RNE-quantize + swizzle weight slices into LDS
    for (int idx = tid; idx < 16 * KTOT; idx += 256) {
        int n = idx & 15;
        int k = idx >> 4;
        Bz[bidx(n, k)] = f2b_rne(Wgs[k * 512 + n0 + n]);
        Bc[bidx(n, k)] = f2b_rne((k < 512) ? Wis[k * 512 + n0 + n]
                                           : Whs[(k - 512) * 512 + n0 + n]);
    }
    __syncthreads();

    const int wave = tid >> 6;
    const int lane = tid & 63;
    const int mloc = lane & 15;               // A-row in tile / D-col
    const int quad = lane >> 4;

    const int arow  = wave * 16 + mloc;       // batch row for A-fragment
    const int dcol  = n0 + mloc;              // H column this lane owns
    const int drow0 = wave * 16 + quad * 4;   // first of 4 owned batch rows

    const float bgv = bgp[layer * 512 + dcol];
    const float biv = bip[layer * 512 + dcol];

    float* myh = (layer == 0) ? h0buf : h1buf;

    float hreg[4] = {0.f, 0.f, 0.f, 0.f};     // own h entries, full fp32

    const int lds_off = (mloc << 10);
    const int swz = mloc & 7;

    // pipelined phases: layer 0 computes t=p, layer 1 computes t=p-1
    unsigned int target = NWG;
    for (int p = 0; p <= S_; ++p) {
        const int t = (layer == 0) ? p : (p - 1);
        if (t >= 0 && t < S_) {
            // x source: layer 0 <- global stream; layer 1 <- h0 "after step t" = parity (t+1)&1
            const float* xp = (layer == 0)
                ? (Xin + ((size_t)arow * S_ + t) * 512 + quad * 8)
                : (h0buf + ((t + 1) & 1) * BH + arow * 512 + quad * 8);
            const float* hp = myh + (t & 1) * BH + arow * 512 + quad * 8;
            float*       hd = myh + ((t + 1) & 1) * BH;

            v4f accz = {0.f, 0.f, 0.f, 0.f};
            v4f accc = {0.f, 0.f, 0.f, 0.f};

            #pragma unroll
            for (int kk = 0; kk < 16; ++kk) {          // k in [0,512): x part
                float4 f0 = *(const float4*)(xp + kk * 32);
                float4 f1 = *(const float4*)(xp + kk * 32 + 4);
                v8s a  = pack8(f0, f1);
                int k8 = (kk * 4 + quad) ^ swz;
                v8s bz = *(const v8s*)(&Bz[lds_off + (k8 << 3)]);
                v8s bc = *(const v8s*)(&Bc[lds_off + (k8 << 3)]);
                accz = __builtin_amdgcn_mfma_f32_16x16x32_bf16(a, bz, accz, 0, 0, 0);
                accc = __builtin_amdgcn_mfma_f32_16x16x32_bf16(a, bc, accc, 0, 0, 0);
            }
            #pragma unroll
            for (int kk = 16; kk < 32; ++kk) {         // k in [512,1024): h part
                float4 f0 = *(const float4*)(hp + (kk - 16) * 32);
                float4 f1 = *(const float4*)(hp + (kk - 16) * 32 + 4);
                v8s a  = pack8(f0, f1);
                int k8 = (kk * 4 + quad) ^ swz;
                v8s bz = *(const v8s*)(&Bz[lds_off + (k8 << 3)]);
                v8s bc = *(const v8s*)(&Bc[lds_off + (k8 << 3)]);
                accz = __builtin_amdgcn_mfma_f32_16x16x32_bf16(a, bz, accz, 0, 0, 0);
                accc = __builtin_amdgcn_mfma_f32_16x16x32_bf16(a, bc, accc, 0, 0, 0);
            }

            #pragma unroll
            for (int i = 0; i < 4; ++i) {
                float zp = accz[i] + bgv;
                float cp = accc[i] + biv;
                zp = fminf(fmaxf(zp, -30.f), 30.f);
                cp = fminf(fmaxf(cp, -15.f), 15.f);
                float z  = 1.f / (1.f + __expf(-zp));
                float e  = __expf(2.f * cp);
                float cc = (e - 1.f) / (e + 1.f);
                float hn = (1.f - z) * hreg[i] + z * cc;
                hreg[i] = hn;
                int row = drow0 + i;
                // agent-scope store: land at coherence point for cross-WG visibility
                __hip_atomic_store(&hd[row * 512 + dcol], hn,
                                   __ATOMIC_RELAXED, __HIP_MEMORY_SCOPE_AGENT);
                if (layer == 1)
                    Yout[((size_t)row * S_ + t) * 512 + dcol] = hn;
            }
        }

        if (p == S_) break;   // last phase needs no trailing barrier

        // device-wide phase barrier (monotonic counter, release/acquire)
        __syncthreads();
        if (tid == 0) {
            __threadfence();                    // release
            atomicAdd(ctr, 1u);
            while (__hip_atomic_load(ctr, __ATOMIC_RELAXED,
                                     __HIP_MEMORY_SCOPE_AGENT) < target) { }
            __threadfence();                    // acquire
        }
        __syncthreads();
        target += NWG;
    }

    #pragma unroll
    for (int i = 0; i < 4; ++i)
        hfin[(size_t)layer * BH + (drow0 + i) * 512 + dcol] = hreg[i];
}

extern "C" void kernel_launch(void* const* d_in, const int* in_sizes, int n_in,
                              void* d_out, int out_size, void* d_ws, size_t ws_size,
                              hipStream_t stream)
{
    const float* x  = (const float*)d_in[0];
    const float* Wg = (const float*)d_in[1];
    const float* bg = (const float*)d_in[2];
    const float* Wi = (const float*)d_in[3];
    const float* bi = (const float*)d_in[4];
    const float* Wh = (const float*)d_in[5];

    float* out = (float*)d_out;                       // (B,S,H)
    float* hid = out + (size_t)B_ * S_ * H_;          // (L,B,H)

    // ws layout (bytes): [h0 dbuf: 2*BH floats = 256KB][h1 dbuf: 256KB][ctr]
    // BUGFIX vs round 3: ctr must sit PAST both fp32 double-buffers (16*BH bytes),
    // not at 8*BH, which aliased h1buf[0] and destroyed the barrier.
    float* h0b = (float*)d_ws;
    float* h1b = h0b + 2 * BH;                                  // floats
    unsigned int* ctr = (unsigned int*)((char*)d_ws + (size_t)16 * BH);  // byte 524288

    hipMemsetAsync(d_ws, 0, (size_t)16 * BH + 1024, stream);    // all state + counter

    gru_fused<<<dim3(NWG), dim3(256), 0, stream>>>(
        x, Wg, bg, Wi, bi, Wh, out, hid, h0b, h1b, ctr);
}